// Round 6
// baseline (468.203 us; speedup 1.0000x reference)
//
#include <hip/hip_runtime.h>
#include <math.h>

#define IN_CH 128
#define OUT_CH 16
#define B 256
#define CH 8192           // edges per sort chunk
#define LSH 6             // leaf = node >> 6  (64 nodes per leaf)
#define LNODES 64
#define PAD 17            // LDS acc row stride (bank-conflict pad)
#define SEG 1024          // edges per hop segment
#define MAXNL 1024
#define MAXG 256

// ================= main path: counting-sort by leaf, segmented LDS hops =================

// --- per-chunk leaf histogram ---
__global__ void k_hist(const int* __restrict__ col, unsigned* __restrict__ bh, int E, int NL) {
    __shared__ unsigned hc[MAXNL];
    for (int i = threadIdx.x; i < NL; i += B) hc[i] = 0u;
    __syncthreads();
    int base = blockIdx.x * CH;
    int end = base + CH < E ? base + CH : E;
    for (int e = base + threadIdx.x; e < end; e += B)
        atomicAdd(&hc[col[e] >> LSH], 1u);
    __syncthreads();
    unsigned* out = bh + (size_t)blockIdx.x * NL;
    for (int i = threadIdx.x; i < NL; i += B) out[i] = hc[i];
}

// --- per-leaf exclusive scan over chunks; totals out (one block per leaf) ---
__global__ void k_colscan(unsigned* __restrict__ bh, unsigned* __restrict__ tot, int G, int NL) {
    int j = blockIdx.x;
    __shared__ unsigned s[B];
    int tid = threadIdx.x;
    unsigned v = (tid < G) ? bh[(size_t)tid * NL + j] : 0u;
    s[tid] = v;
    __syncthreads();
    for (int off = 1; off < B; off <<= 1) {
        unsigned add = (tid >= off) ? s[tid - off] : 0u;
        __syncthreads();
        s[tid] += add;
        __syncthreads();
    }
    unsigned excl = s[tid] - v;
    if (tid < G) bh[(size_t)tid * NL + j] = excl;
    if (tid == B - 1) tot[j] = s[tid];
}

// --- scan leaf totals -> ptr[NL+1]; scan ceil(tot/SEG) -> segptr[NL+1] (one block) ---
__global__ void k_scanptr(const unsigned* __restrict__ tot, unsigned* __restrict__ ptr,
                          unsigned* __restrict__ segptr, int NL) {
    __shared__ unsigned sums[B];
    int tid = threadIdx.x;
    int base = tid * 4;
    // pass 1: edge prefix
    unsigned v[4]; unsigned loc = 0;
#pragma unroll
    for (int q = 0; q < 4; ++q) {
        int i = base + q;
        v[q] = (i < NL) ? tot[i] : 0u;
        loc += v[q];
    }
    sums[tid] = loc;
    __syncthreads();
    for (int off = 1; off < B; off <<= 1) {
        unsigned add = (tid >= off) ? sums[tid - off] : 0u;
        __syncthreads();
        sums[tid] += add;
        __syncthreads();
    }
    unsigned run = sums[tid] - loc;
#pragma unroll
    for (int q = 0; q < 4; ++q) {
        int i = base + q;
        if (i < NL) ptr[i] = run;
        run += v[q];
    }
    if (tid == B - 1) ptr[NL] = run;
    __syncthreads();
    // pass 2: segment prefix
    unsigned w[4]; loc = 0;
#pragma unroll
    for (int q = 0; q < 4; ++q) {
        int i = base + q;
        w[q] = (i < NL) ? (tot[i] + SEG - 1) / SEG : 0u;
        loc += w[q];
    }
    sums[tid] = loc;
    __syncthreads();
    for (int off = 1; off < B; off <<= 1) {
        unsigned add = (tid >= off) ? sums[tid - off] : 0u;
        __syncthreads();
        sums[tid] += add;
        __syncthreads();
    }
    run = sums[tid] - loc;
#pragma unroll
    for (int q = 0; q < 4; ++q) {
        int i = base + q;
        if (i < NL) segptr[i] = run;
        run += w[q];
    }
    if (tid == B - 1) segptr[NL] = run;
}

// --- placement: scatter edges into leaf-grouped arrays ---
__global__ void k_place(const int* __restrict__ row, const int* __restrict__ col,
                        const float* __restrict__ ew, const unsigned* __restrict__ bh,
                        const unsigned* __restrict__ ptr,
                        unsigned short* __restrict__ srow, unsigned char* __restrict__ scl,
                        float* __restrict__ sew, int E, int NL) {
    __shared__ unsigned ctr[MAXNL];
    const unsigned* myb = bh + (size_t)blockIdx.x * NL;
    for (int i = threadIdx.x; i < NL; i += B) ctr[i] = ptr[i] + myb[i];
    __syncthreads();
    int base = blockIdx.x * CH;
    int end = base + CH < E ? base + CH : E;
    for (int e = base + threadIdx.x; e < end; e += B) {
        int c = col[e];
        unsigned pos = atomicAdd(&ctr[c >> LSH], 1u);
        srow[pos] = (unsigned short)row[e];
        scl[pos]  = (unsigned char)(c & (LNODES - 1));
        sew[pos]  = ew[e];
    }
}

// --- binary search: largest l with segptr[l] <= b ---
__device__ __forceinline__ int find_leaf(const unsigned* __restrict__ segptr, int NL, unsigned b) {
    int lo = 0, hi = NL - 1;
    while (lo < hi) {
        int mid = (lo + hi + 1) >> 1;
        if (segptr[mid] <= b) lo = mid; else hi = mid - 1;
    }
    return lo;
}

// --- segmented degree accumulation ---
__global__ void __launch_bounds__(B)
k_deg(const unsigned char* __restrict__ scl, const float* __restrict__ sew,
      const unsigned* __restrict__ ptr, const unsigned* __restrict__ segptr,
      float* __restrict__ deg, int N, int NL) {
    unsigned b = blockIdx.x;
    if (b >= segptr[NL]) return;
    int l = find_leaf(segptr, NL, b);
    int seg = (int)ptr[l] + (int)(b - segptr[l]) * SEG;
    int end = (int)ptr[l + 1];
    if (seg + SEG < end) end = seg + SEG;
    __shared__ float dacc[LNODES];
    int tid = threadIdx.x;
    if (tid < LNODES) dacc[tid] = 0.f;
    __syncthreads();
    for (int j = seg + tid; j < end; j += B)
        atomicAdd(&dacc[scl[j]], sew[j]);
    __syncthreads();
    if (tid < LNODES) {
        int n = l * LNODES + tid;
        if (n < N && dacc[tid] != 0.f) atomicAdd(&deg[n], dacc[tid]);
    }
}

__global__ void k_dinv(const float* __restrict__ deg, float* __restrict__ dinv, int N) {
    int i = blockIdx.x * blockDim.x + threadIdx.x;
    if (i < N) dinv[i] = rsqrtf(1.0f + deg[i]);
}

// --- projection: h0 = x @ W^T ---
__global__ void k_proj(const float* __restrict__ x, const float* __restrict__ W,
                       float* __restrict__ y, int N) {
    __shared__ float sW[OUT_CH * (IN_CH + 1)];
    for (int i = threadIdx.x; i < OUT_CH * IN_CH; i += blockDim.x) {
        int o = i >> 7, k = i & 127;
        sW[o * (IN_CH + 1) + k] = W[i];
    }
    __syncthreads();
    int t = threadIdx.x;
    int n = blockIdx.x * 16 + (t >> 4);
    int o = t & 15;
    if (n >= N) return;
    const float* xr = x + (size_t)n * IN_CH;
    const float* wr = sW + o * (IN_CH + 1);
    float acc = 0.0f;
#pragma unroll
    for (int k = 0; k < IN_CH; k += 4) {
        float4 xv = *reinterpret_cast<const float4*>(xr + k);
        acc += xv.x * wr[k] + xv.y * wr[k + 1] + xv.z * wr[k + 2] + xv.w * wr[k + 3];
    }
    y[(size_t)n * OUT_CH + o] = acc;
}

// --- segmented hop: partial LDS accumulate + atomic flush into hc ---
__global__ void __launch_bounds__(B)
k_hop(const unsigned short* __restrict__ srow, const unsigned char* __restrict__ scl,
      const float* __restrict__ sew, const unsigned* __restrict__ ptr,
      const unsigned* __restrict__ segptr, const float* __restrict__ dinv,
      const float* __restrict__ hin, float* __restrict__ hc, int N, int NL) {
    unsigned b = blockIdx.x;
    if (b >= segptr[NL]) return;
    int l = find_leaf(segptr, NL, b);
    int seg = (int)ptr[l] + (int)(b - segptr[l]) * SEG;
    int end = (int)ptr[l + 1];
    if (seg + SEG < end) end = seg + SEG;
    int cnt = end - seg;

    __shared__ float acc[LNODES * PAD];
    __shared__ float dloc[LNODES];
    int tid = threadIdx.x;
    for (int i = tid; i < LNODES * PAD; i += B) acc[i] = 0.f;
    if (tid < LNODES) {
        int n = l * LNODES + tid;
        dloc[tid] = (n < N) ? dinv[n] : 0.f;
    }
    __syncthreads();

    int ch = tid & 15;
    for (int j = tid; j < cnt * OUT_CH; j += B) {
        int e = seg + (j >> 4);
        int c6 = scl[e];
        int r = srow[e];
        float nv = dinv[r] * sew[e] * dloc[c6];
        atomicAdd(&acc[c6 * PAD + ch], nv * hin[(size_t)r * OUT_CH + ch]);
    }
    __syncthreads();

    for (int i = tid; i < LNODES * OUT_CH; i += B) {
        int n = l * LNODES + (i >> 4);
        float v = acc[(i >> 4) * PAD + (i & 15)];
        if (n < N && v != 0.f)
            atomicAdd(&hc[(size_t)n * OUT_CH + (i & 15)], v);
    }
}

// --- hop1 reduce (in place): h0 = dinv^2*h0 + hc; re-zero hc ---
__global__ void k_red1(float* __restrict__ h, const float* __restrict__ dinv,
                       float* __restrict__ hc, int N) {
    int i4 = blockIdx.x * blockDim.x + threadIdx.x;
    int n4 = N * (OUT_CH / 4);
    if (i4 >= n4) return;
    float d = dinv[i4 >> 2];
    float s = d * d;
    float4 a = reinterpret_cast<float4*>(h)[i4];
    float4 c = reinterpret_cast<float4*>(hc)[i4];
    a.x = a.x * s + c.x; a.y = a.y * s + c.y;
    a.z = a.z * s + c.z; a.w = a.w * s + c.w;
    reinterpret_cast<float4*>(h)[i4] = a;
    reinterpret_cast<float4*>(hc)[i4] = make_float4(0.f, 0.f, 0.f, 0.f);
}

// --- hop2 reduce fused with log_softmax ---
__global__ void k_red2_lsm(const float* __restrict__ h, const float* __restrict__ dinv,
                           const float* __restrict__ hc, float* __restrict__ out, int N) {
    int n = blockIdx.x * blockDim.x + threadIdx.x;
    if (n >= N) return;
    size_t base = (size_t)n * OUT_CH;
    float d = dinv[n];
    float s = d * d;
    float v[OUT_CH];
    float4* vv = reinterpret_cast<float4*>(v);
#pragma unroll
    for (int q = 0; q < 4; ++q) {
        float4 a = reinterpret_cast<const float4*>(h + base)[q];
        float4 c = reinterpret_cast<const float4*>(hc + base)[q];
        vv[q] = make_float4(a.x * s + c.x, a.y * s + c.y, a.z * s + c.z, a.w * s + c.w);
    }
    float m = v[0];
#pragma unroll
    for (int i = 1; i < OUT_CH; i++) m = fmaxf(m, v[i]);
    float sum = 0.0f;
#pragma unroll
    for (int i = 0; i < OUT_CH; i++) sum += expf(v[i] - m);
    float lse = m + logf(sum);
    float* orow = out + base;
#pragma unroll
    for (int i = 0; i < OUT_CH; i++) orow[i] = v[i] - lse;
}

__global__ void k_zero4(float4* p, long long n4) {
    long long stride = (long long)gridDim.x * blockDim.x;
    for (long long i = (long long)blockIdx.x * blockDim.x + threadIdx.x; i < n4; i += stride)
        p[i] = make_float4(0.f, 0.f, 0.f, 0.f);
}

// ================= fallback path (proven r2 structure) =================

__global__ void fb_deginit(float* deg, int N) {
    int i = blockIdx.x * blockDim.x + threadIdx.x;
    if (i < N) deg[i] = 1.0f;
}
__global__ void fb_deg(const int* __restrict__ col, const float* __restrict__ ew,
                       float* deg, int E) {
    int e = blockIdx.x * blockDim.x + threadIdx.x;
    if (e < E) atomicAdd(&deg[col[e]], ew[e]);
}
__global__ void fb_dinv(const float* __restrict__ deg, float* dinv, int N) {
    int i = blockIdx.x * blockDim.x + threadIdx.x;
    if (i < N) dinv[i] = rsqrtf(deg[i]);
}
__global__ void fb_selfinit(const float* __restrict__ hin, const float* __restrict__ dinv,
                            float* __restrict__ hout, int N) {
    int idx = blockIdx.x * blockDim.x + threadIdx.x;
    if (idx < N * OUT_CH) {
        float d = dinv[idx >> 4];
        hout[idx] = d * d * hin[idx];
    }
}
__global__ void fb_scat(const int* __restrict__ row, const int* __restrict__ col,
                        const float* __restrict__ ew, const float* __restrict__ dinv,
                        const float* __restrict__ hin, float* __restrict__ hout, int E) {
    long long idx = (long long)blockIdx.x * blockDim.x + threadIdx.x;
    int e = (int)(idx >> 4);
    int c = (int)(idx & 15);
    if (e >= E) return;
    int r = row[e], cl = col[e];
    float nv = dinv[r] * ew[e] * dinv[cl];
    atomicAdd(&hout[(size_t)cl * OUT_CH + c], nv * hin[(size_t)r * OUT_CH + c]);
}
__global__ void fb_lsm(const float* __restrict__ h, float* __restrict__ out, int N) {
    int n = blockIdx.x * blockDim.x + threadIdx.x;
    if (n >= N) return;
    const float* hr = h + (size_t)n * OUT_CH;
    float v[OUT_CH];
#pragma unroll
    for (int i = 0; i < OUT_CH; i++) v[i] = hr[i];
    float m = v[0];
#pragma unroll
    for (int i = 1; i < OUT_CH; i++) m = fmaxf(m, v[i]);
    float s = 0.0f;
#pragma unroll
    for (int i = 0; i < OUT_CH; i++) s += expf(v[i] - m);
    float lse = m + logf(s);
    float* orow = out + (size_t)n * OUT_CH;
#pragma unroll
    for (int i = 0; i < OUT_CH; i++) orow[i] = v[i] - lse;
}

// ================= launch =================

extern "C" void kernel_launch(void* const* d_in, const int* in_sizes, int n_in,
                              void* d_out, int out_size, void* d_ws, size_t ws_size,
                              hipStream_t stream) {
    const float* x  = (const float*)d_in[0];
    const float* W  = (const float*)d_in[1];
    const float* ew = (const float*)d_in[2];
    const int*   ei = (const int*)d_in[3];  // harness pushes int64 as int32

    int N = in_sizes[0] / IN_CH;
    int E = in_sizes[2];
    const int* row = ei;       // source
    const int* col = ei + E;   // target

    auto al = [](size_t v) { return (v + 255) & ~(size_t)255; };
    size_t N16 = (size_t)N * OUT_CH;

    int NL = (N + LNODES - 1) >> LSH;
    int G  = (E + CH - 1) / CH;

    // layout: bh aliases h0 (bh dead before k_proj writes h0)
    size_t o_h0   = 0;
    size_t sz_h0  = al(N16 * 4);
    size_t sz_bh  = al((size_t)G * NL * 4);
    size_t o_tot  = o_h0  + (sz_h0 > sz_bh ? sz_h0 : sz_bh);
    size_t o_ptr  = o_tot + al((size_t)NL * 4);
    size_t o_segp = o_ptr + al((size_t)(NL + 1) * 4);
    size_t o_srow = o_segp + al((size_t)(NL + 1) * 4);
    size_t o_scl  = o_srow + al((size_t)E * 2);
    size_t o_sew  = o_scl  + al((size_t)E);
    size_t o_dinv = o_sew  + al((size_t)E * 4);
    size_t o_deg  = o_dinv + al((size_t)N * 4);   // zero region start
    size_t o_hc   = o_deg  + al((size_t)N * 4);
    size_t need   = o_hc   + al(N16 * 4);

    char* ws = (char*)d_ws;

    if (NL <= MAXNL && G <= MAXG && N <= 65536 && need <= ws_size) {
        float*          h0   = (float*)(ws + o_h0);
        unsigned*       bh   = (unsigned*)(ws + o_h0);
        unsigned*       tot  = (unsigned*)(ws + o_tot);
        unsigned*       ptr  = (unsigned*)(ws + o_ptr);
        unsigned*       segp = (unsigned*)(ws + o_segp);
        unsigned short* srow = (unsigned short*)(ws + o_srow);
        unsigned char*  scl  = (unsigned char*)(ws + o_scl);
        float*          sew  = (float*)(ws + o_sew);
        float*          dinv = (float*)(ws + o_dinv);
        float*          deg  = (float*)(ws + o_deg);
        float*          hc   = (float*)(ws + o_hc);

        // zero deg + hc (contiguous)
        long long z4 = (long long)(need - o_deg) / 16;
        int gz = (int)((z4 + B - 1) / B);
        if (gz > 2048) gz = 2048;
        k_zero4<<<gz, B, 0, stream>>>((float4*)(ws + o_deg), z4);

        int UB = (E + SEG - 1) / SEG + NL;  // upper bound on segments

        k_hist   <<<G,  B, 0, stream>>>(col, bh, E, NL);
        k_colscan<<<NL, B, 0, stream>>>(bh, tot, G, NL);
        k_scanptr<<<1,  B, 0, stream>>>(tot, ptr, segp, NL);
        k_place  <<<G,  B, 0, stream>>>(row, col, ew, bh, ptr, srow, scl, sew, E, NL);
        k_deg    <<<UB, B, 0, stream>>>(scl, sew, ptr, segp, deg, N, NL);
        k_dinv   <<<(N + B - 1) / B, B, 0, stream>>>(deg, dinv, N);
        k_proj   <<<(N + 15) / 16, B, 0, stream>>>(x, W, h0, N);  // clobbers bh (dead)
        k_hop    <<<UB, B, 0, stream>>>(srow, scl, sew, ptr, segp, dinv, h0, hc, N, NL);
        int g4 = (int)((N16 / 4 + B - 1) / B);
        k_red1   <<<g4, B, 0, stream>>>(h0, dinv, hc, N);
        k_hop    <<<UB, B, 0, stream>>>(srow, scl, sew, ptr, segp, dinv, h0, hc, N, NL);
        k_red2_lsm<<<(N + B - 1) / B, B, 0, stream>>>(h0, dinv, hc, (float*)d_out, N);
    } else {
        // ---- fallback (r2-style, ~6.8 MB ws) ----
        size_t f_deg  = 0;
        size_t f_dinv = f_deg  + al((size_t)N * 4);
        size_t f_h0   = f_dinv + al((size_t)N * 4);
        size_t f_h1   = f_h0   + al(N16 * 4);
        float* deg  = (float*)(ws + f_deg);
        float* dinv = (float*)(ws + f_dinv);
        float* h0   = (float*)(ws + f_h0);
        float* h1   = (float*)(ws + f_h1);

        int gN   = (N + B - 1) / B;
        int gE   = (E + B - 1) / B;
        int gN16 = (N * OUT_CH + B - 1) / B;
        long long scat = (long long)E * OUT_CH;
        int gScat = (int)((scat + B - 1) / B);

        fb_deginit<<<gN, B, 0, stream>>>(deg, N);
        fb_deg<<<gE, B, 0, stream>>>(col, ew, deg, E);
        fb_dinv<<<gN, B, 0, stream>>>(deg, dinv, N);
        k_proj<<<(N + 15) / 16, B, 0, stream>>>(x, W, h0, N);
        float* hin = h0; float* hout = h1;
        for (int k = 0; k < 2; k++) {
            fb_selfinit<<<gN16, B, 0, stream>>>(hin, dinv, hout, N);
            fb_scat<<<gScat, B, 0, stream>>>(row, col, ew, dinv, hin, hout, E);
            float* t = hin; hin = hout; hout = t;
        }
        fb_lsm<<<gN, B, 0, stream>>>(hin, (float*)d_out, N);
    }
}

// Round 7
// 181.484 us; speedup vs baseline: 2.5799x; 2.5799x over previous
//
#include <hip/hip_runtime.h>
#include <math.h>

#define IN_CH 128
#define OUT_CH 16
#define B 256
#define CH 8192           // edges per sort chunk
#define LSH 6             // leaf = node >> 6  (64 nodes per leaf)
#define LNODES 64
#define MAXNL 1024
#define MAXG 256

// ================= main path: two-level counting sort -> per-node CSR hops =================

// --- per-chunk leaf histogram ---
__global__ void k_hist(const int* __restrict__ col, unsigned* __restrict__ bh, int E, int NL) {
    __shared__ unsigned hc[MAXNL];
    for (int i = threadIdx.x; i < NL; i += B) hc[i] = 0u;
    __syncthreads();
    int base = blockIdx.x * CH;
    int end = base + CH < E ? base + CH : E;
    for (int e = base + threadIdx.x; e < end; e += B)
        atomicAdd(&hc[col[e] >> LSH], 1u);
    __syncthreads();
    unsigned* out = bh + (size_t)blockIdx.x * NL;
    for (int i = threadIdx.x; i < NL; i += B) out[i] = hc[i];
}

// --- per-leaf exclusive scan over chunks; totals out ---
__global__ void k_colscan(unsigned* __restrict__ bh, unsigned* __restrict__ tot, int G, int NL) {
    int j = blockIdx.x;
    __shared__ unsigned s[B];
    int tid = threadIdx.x;
    unsigned v = (tid < G) ? bh[(size_t)tid * NL + j] : 0u;
    s[tid] = v;
    __syncthreads();
    for (int off = 1; off < B; off <<= 1) {
        unsigned add = (tid >= off) ? s[tid - off] : 0u;
        __syncthreads();
        s[tid] += add;
        __syncthreads();
    }
    unsigned excl = s[tid] - v;
    if (tid < G) bh[(size_t)tid * NL + j] = excl;
    if (tid == B - 1) tot[j] = s[tid];
}

// --- scan leaf totals -> ptr[NL+1]; also nodeptr[N] = E ---
__global__ void k_scanptr(const unsigned* __restrict__ tot, unsigned* __restrict__ ptr,
                          unsigned* __restrict__ nodeptr, int NL, int N) {
    __shared__ unsigned sums[B];
    int tid = threadIdx.x;
    int base = tid * 4;
    unsigned v[4]; unsigned loc = 0;
#pragma unroll
    for (int q = 0; q < 4; ++q) {
        int i = base + q;
        v[q] = (i < NL) ? tot[i] : 0u;
        loc += v[q];
    }
    sums[tid] = loc;
    __syncthreads();
    for (int off = 1; off < B; off <<= 1) {
        unsigned add = (tid >= off) ? sums[tid - off] : 0u;
        __syncthreads();
        sums[tid] += add;
        __syncthreads();
    }
    unsigned run = sums[tid] - loc;
#pragma unroll
    for (int q = 0; q < 4; ++q) {
        int i = base + q;
        if (i < NL) ptr[i] = run;
        run += v[q];
    }
    if (tid == B - 1) { ptr[NL] = run; nodeptr[N] = run; }
}

// --- placement: scatter edges into leaf-grouped arrays ---
__global__ void k_place(const int* __restrict__ row, const int* __restrict__ col,
                        const float* __restrict__ ew, const unsigned* __restrict__ bh,
                        const unsigned* __restrict__ ptr,
                        unsigned short* __restrict__ srow, unsigned char* __restrict__ scl,
                        float* __restrict__ sew, int E, int NL) {
    __shared__ unsigned ctr[MAXNL];
    const unsigned* myb = bh + (size_t)blockIdx.x * NL;
    for (int i = threadIdx.x; i < NL; i += B) ctr[i] = ptr[i] + myb[i];
    __syncthreads();
    int base = blockIdx.x * CH;
    int end = base + CH < E ? base + CH : E;
    for (int e = base + threadIdx.x; e < end; e += B) {
        int c = col[e];
        unsigned pos = atomicAdd(&ctr[c >> LSH], 1u);
        srow[pos] = (unsigned short)row[e];
        scl[pos]  = (unsigned char)(c & (LNODES - 1));
        sew[pos]  = ew[e];
    }
}

// --- second-level sort (by node within leaf) + degree -> dinv + nodeptr ---
__global__ void __launch_bounds__(B)
k_sort2(const unsigned short* __restrict__ srow, const unsigned char* __restrict__ scl,
        const float* __restrict__ sew, const unsigned* __restrict__ ptr,
        unsigned short* __restrict__ srow2, float* __restrict__ sew2,
        unsigned* __restrict__ nodeptr, float* __restrict__ dinv, int N) {
    __shared__ unsigned hist[LNODES];
    __shared__ float dacc[LNODES];
    __shared__ unsigned start[LNODES];
    int l = blockIdx.x, tid = threadIdx.x;
    if (tid < LNODES) { hist[tid] = 0u; dacc[tid] = 0.f; }
    __syncthreads();
    int seg = (int)ptr[l], end = (int)ptr[l + 1];
    for (int j = seg + tid; j < end; j += B) {
        int c = scl[j];
        atomicAdd(&hist[c], 1u);
        atomicAdd(&dacc[c], sew[j]);
    }
    __syncthreads();
    if (tid < LNODES) {  // tid<64: exactly one wave -> shfl scan
        unsigned v = hist[tid];
        unsigned sum = v;
        for (int off = 1; off < LNODES; off <<= 1) {
            unsigned o = __shfl_up(sum, off, 64);
            if (tid >= off) sum += o;
        }
        unsigned st = (unsigned)seg + sum - v;  // exclusive
        start[tid] = st;
        int n = l * LNODES + tid;
        if (n < N) {
            nodeptr[n] = st;
            dinv[n] = rsqrtf(1.0f + dacc[tid]);
        }
    }
    __syncthreads();
    for (int j = seg + tid; j < end; j += B) {
        int c = scl[j];
        unsigned pos = atomicAdd(&start[c], 1u);
        srow2[pos] = srow[j];
        sew2[pos]  = sew[j];
    }
}

// --- fold dinv[src] into edge weight ---
__global__ void k_prescale(const unsigned short* __restrict__ srow2, float* __restrict__ sew2,
                           const float* __restrict__ dinv, int E) {
    int j = blockIdx.x * B + threadIdx.x;
    if (j < E) sew2[j] *= dinv[srow2[j]];
}

// --- projection: h0 = x @ W^T ---
__global__ void k_proj(const float* __restrict__ x, const float* __restrict__ W,
                       float* __restrict__ y, int N) {
    __shared__ float sW[OUT_CH * (IN_CH + 1)];
    for (int i = threadIdx.x; i < OUT_CH * IN_CH; i += blockDim.x) {
        int o = i >> 7, k = i & 127;
        sW[o * (IN_CH + 1) + k] = W[i];
    }
    __syncthreads();
    int t = threadIdx.x;
    int n = blockIdx.x * 16 + (t >> 4);
    int o = t & 15;
    if (n >= N) return;
    const float* xr = x + (size_t)n * IN_CH;
    const float* wr = sW + o * (IN_CH + 1);
    float acc = 0.0f;
#pragma unroll
    for (int k = 0; k < IN_CH; k += 4) {
        float4 xv = *reinterpret_cast<const float4*>(xr + k);
        acc += xv.x * wr[k] + xv.y * wr[k + 1] + xv.z * wr[k + 2] + xv.w * wr[k + 3];
    }
    y[(size_t)n * OUT_CH + o] = acc;
}

// --- CSR hop: 16 threads per node, register accumulation, no atomics ---
template <bool FINAL>
__global__ void __launch_bounds__(B)
k_hop_csr(const unsigned short* __restrict__ srow2, const float* __restrict__ sew2,
          const unsigned* __restrict__ nodeptr, const float* __restrict__ dinv,
          const float* __restrict__ hin, float* __restrict__ hout, int N) {
    int t = blockIdx.x * B + threadIdx.x;
    int n = t >> 4, ch = t & 15;
    if (n >= N) return;
    int j0 = (int)nodeptr[n], j1 = (int)nodeptr[n + 1];
    float acc = 0.f;
    int j = j0;
    for (; j + 1 < j1; j += 2) {  // 2-wide for ILP
        int r0 = srow2[j], r1 = srow2[j + 1];
        float w0 = sew2[j], w1 = sew2[j + 1];
        acc += w0 * hin[(size_t)r0 * OUT_CH + ch] + w1 * hin[(size_t)r1 * OUT_CH + ch];
    }
    if (j < j1) {
        int r = srow2[j];
        acc += sew2[j] * hin[(size_t)r * OUT_CH + ch];
    }
    float d = dinv[n];
    float v = d * (d * hin[(size_t)n * OUT_CH + ch] + acc);
    if (!FINAL) {
        hout[(size_t)n * OUT_CH + ch] = v;
    } else {
        float m = v;
#pragma unroll
        for (int off = 1; off < 16; off <<= 1) m = fmaxf(m, __shfl_xor(m, off, 16));
        float s = expf(v - m);
#pragma unroll
        for (int off = 1; off < 16; off <<= 1) s += __shfl_xor(s, off, 16);
        hout[(size_t)n * OUT_CH + ch] = v - m - logf(s);
    }
}

// ================= fallback path (proven r2 structure) =================

__global__ void fb_deginit(float* deg, int N) {
    int i = blockIdx.x * blockDim.x + threadIdx.x;
    if (i < N) deg[i] = 1.0f;
}
__global__ void fb_deg(const int* __restrict__ col, const float* __restrict__ ew,
                       float* deg, int E) {
    int e = blockIdx.x * blockDim.x + threadIdx.x;
    if (e < E) atomicAdd(&deg[col[e]], ew[e]);
}
__global__ void fb_dinv(const float* __restrict__ deg, float* dinv, int N) {
    int i = blockIdx.x * blockDim.x + threadIdx.x;
    if (i < N) dinv[i] = rsqrtf(deg[i]);
}
__global__ void fb_selfinit(const float* __restrict__ hin, const float* __restrict__ dinv,
                            float* __restrict__ hout, int N) {
    int idx = blockIdx.x * blockDim.x + threadIdx.x;
    if (idx < N * OUT_CH) {
        float d = dinv[idx >> 4];
        hout[idx] = d * d * hin[idx];
    }
}
__global__ void fb_scat(const int* __restrict__ row, const int* __restrict__ col,
                        const float* __restrict__ ew, const float* __restrict__ dinv,
                        const float* __restrict__ hin, float* __restrict__ hout, int E) {
    long long idx = (long long)blockIdx.x * blockDim.x + threadIdx.x;
    int e = (int)(idx >> 4);
    int c = (int)(idx & 15);
    if (e >= E) return;
    int r = row[e], cl = col[e];
    float nv = dinv[r] * ew[e] * dinv[cl];
    atomicAdd(&hout[(size_t)cl * OUT_CH + c], nv * hin[(size_t)r * OUT_CH + c]);
}
__global__ void fb_lsm(const float* __restrict__ h, float* __restrict__ out, int N) {
    int n = blockIdx.x * blockDim.x + threadIdx.x;
    if (n >= N) return;
    const float* hr = h + (size_t)n * OUT_CH;
    float v[OUT_CH];
#pragma unroll
    for (int i = 0; i < OUT_CH; i++) v[i] = hr[i];
    float m = v[0];
#pragma unroll
    for (int i = 1; i < OUT_CH; i++) m = fmaxf(m, v[i]);
    float s = 0.0f;
#pragma unroll
    for (int i = 0; i < OUT_CH; i++) s += expf(v[i] - m);
    float lse = m + logf(s);
    float* orow = out + (size_t)n * OUT_CH;
#pragma unroll
    for (int i = 0; i < OUT_CH; i++) orow[i] = v[i] - lse;
}

// ================= launch =================

extern "C" void kernel_launch(void* const* d_in, const int* in_sizes, int n_in,
                              void* d_out, int out_size, void* d_ws, size_t ws_size,
                              hipStream_t stream) {
    const float* x  = (const float*)d_in[0];
    const float* W  = (const float*)d_in[1];
    const float* ew = (const float*)d_in[2];
    const int*   ei = (const int*)d_in[3];  // harness pushes int64 as int32

    int N = in_sizes[0] / IN_CH;
    int E = in_sizes[2];
    const int* row = ei;       // source
    const int* col = ei + E;   // target

    auto al = [](size_t v) { return (v + 255) & ~(size_t)255; };
    size_t N16 = (size_t)N * OUT_CH;

    int NL = (N + LNODES - 1) >> LSH;
    int G  = (E + CH - 1) / CH;

    auto mx = [](size_t a, size_t b) { return a > b ? a : b; };

    // layout with aliasing:
    //   srow2 | sew2(∪bh) | srow(∪h0) | scl+sew(∪h1) | tot | ptr | nodeptr | dinv
    size_t o_srow2 = 0;
    size_t o_sew2  = o_srow2 + al((size_t)E * 2);
    size_t o_srow  = o_sew2  + mx(al((size_t)E * 4), al((size_t)G * NL * 4));
    size_t o_scl   = o_srow  + mx(al((size_t)E * 2), al(N16 * 4));
    size_t o_sew   = o_scl   + al((size_t)E);
    size_t end_b   = o_sew   + al((size_t)E * 4);
    size_t o_tot   = mx(end_b, o_scl + al(N16 * 4));  // h1 spans scl..sew region
    size_t o_ptr   = o_tot   + al((size_t)NL * 4);
    size_t o_nptr  = o_ptr   + al((size_t)(NL + 1) * 4);
    size_t o_dinv  = o_nptr  + al((size_t)(N + 1) * 4);
    size_t need    = o_dinv  + al((size_t)N * 4);

    char* ws = (char*)d_ws;

    if (NL <= MAXNL && G <= MAXG && N <= 65536 && need <= ws_size) {
        unsigned short* srow2 = (unsigned short*)(ws + o_srow2);
        float*          sew2  = (float*)(ws + o_sew2);
        unsigned*       bh    = (unsigned*)(ws + o_sew2);   // dead before sew2 written
        unsigned short* srow  = (unsigned short*)(ws + o_srow);
        float*          h0    = (float*)(ws + o_srow);      // written after srow dead
        unsigned char*  scl   = (unsigned char*)(ws + o_scl);
        float*          sew   = (float*)(ws + o_sew);
        float*          h1    = (float*)(ws + o_scl);       // written after scl/sew dead
        unsigned*       tot   = (unsigned*)(ws + o_tot);
        unsigned*       ptr   = (unsigned*)(ws + o_ptr);
        unsigned*       nptr  = (unsigned*)(ws + o_nptr);
        float*          dinv  = (float*)(ws + o_dinv);

        k_hist    <<<G,  B, 0, stream>>>(col, bh, E, NL);
        k_colscan <<<NL, B, 0, stream>>>(bh, tot, G, NL);
        k_scanptr <<<1,  B, 0, stream>>>(tot, ptr, nptr, NL, N);
        k_place   <<<G,  B, 0, stream>>>(row, col, ew, bh, ptr, srow, scl, sew, E, NL);
        k_sort2   <<<NL, B, 0, stream>>>(srow, scl, sew, ptr, srow2, sew2, nptr, dinv, N);
        k_prescale<<<(E + B - 1) / B, B, 0, stream>>>(srow2, sew2, dinv, E);
        k_proj    <<<(N + 15) / 16, B, 0, stream>>>(x, W, h0, N);   // clobbers srow (dead)
        int gH = (int)(((size_t)N * OUT_CH + B - 1) / B);
        k_hop_csr<false><<<gH, B, 0, stream>>>(srow2, sew2, nptr, dinv, h0, h1, N);  // clobbers scl/sew (dead)
        k_hop_csr<true ><<<gH, B, 0, stream>>>(srow2, sew2, nptr, dinv, h1, (float*)d_out, N);
    } else {
        // ---- fallback (r2-style, ~6.8 MB ws) ----
        size_t f_deg  = 0;
        size_t f_dinv = f_deg  + al((size_t)N * 4);
        size_t f_h0   = f_dinv + al((size_t)N * 4);
        size_t f_h1   = f_h0   + al(N16 * 4);
        float* deg  = (float*)(ws + f_deg);
        float* dinv = (float*)(ws + f_dinv);
        float* h0   = (float*)(ws + f_h0);
        float* h1   = (float*)(ws + f_h1);

        int gN   = (N + B - 1) / B;
        int gE   = (E + B - 1) / B;
        int gN16 = (N * OUT_CH + B - 1) / B;
        long long scat = (long long)E * OUT_CH;
        int gScat = (int)((scat + B - 1) / B);

        fb_deginit<<<gN, B, 0, stream>>>(deg, N);
        fb_deg<<<gE, B, 0, stream>>>(col, ew, deg, E);
        fb_dinv<<<gN, B, 0, stream>>>(deg, dinv, N);
        k_proj<<<(N + 15) / 16, B, 0, stream>>>(x, W, h0, N);
        float* hin = h0; float* hout = h1;
        for (int k = 0; k < 2; k++) {
            fb_selfinit<<<gN16, B, 0, stream>>>(hin, dinv, hout, N);
            fb_scat<<<gScat, B, 0, stream>>>(row, col, ew, dinv, hin, hout, E);
            float* t = hin; hin = hout; hout = t;
        }
        fb_lsm<<<gN, B, 0, stream>>>(hin, (float*)d_out, N);
    }
}

// Round 8
// 155.293 us; speedup vs baseline: 3.0150x; 1.1687x over previous
//
#include <hip/hip_runtime.h>
#include <math.h>

#define IN_CH 128
#define OUT_CH 16
#define B 256
#define CH 4096           // edges per sort chunk
#define LSH 6             // leaf = node >> 6  (64 nodes per leaf)
#define LNODES 64
#define MAXNL 1024
#define MAXG 512

// ================= main path: two-level counting sort -> per-node CSR hops =================

// --- per-chunk leaf histogram ---
__global__ void k_hist(const int* __restrict__ col, unsigned* __restrict__ bh, int E, int NL) {
    __shared__ unsigned hc[MAXNL];
    for (int i = threadIdx.x; i < NL; i += B) hc[i] = 0u;
    __syncthreads();
    int base = blockIdx.x * CH;
    int end = base + CH < E ? base + CH : E;
    for (int e = base + threadIdx.x; e < end; e += B)
        atomicAdd(&hc[col[e] >> LSH], 1u);
    __syncthreads();
    unsigned* out = bh + (size_t)blockIdx.x * NL;
    for (int i = threadIdx.x; i < NL; i += B) out[i] = hc[i];
}

// --- per-leaf exclusive scan over chunks (loops over G with carry); totals out ---
__global__ void k_colscan(unsigned* __restrict__ bh, unsigned* __restrict__ tot, int G, int NL) {
    int j = blockIdx.x;
    __shared__ unsigned s[B];
    int tid = threadIdx.x;
    unsigned carry = 0;
    for (int g0 = 0; g0 < G; g0 += B) {
        __syncthreads();
        int g = g0 + tid;
        unsigned v = (g < G) ? bh[(size_t)g * NL + j] : 0u;
        s[tid] = v;
        __syncthreads();
        for (int off = 1; off < B; off <<= 1) {
            unsigned add = (tid >= off) ? s[tid - off] : 0u;
            __syncthreads();
            s[tid] += add;
            __syncthreads();
        }
        if (g < G) bh[(size_t)g * NL + j] = carry + s[tid] - v;
        carry += s[B - 1];
    }
    if (tid == 0) tot[j] = carry;
}

// --- scan leaf totals -> ptr[NL+1]; also nodeptr[N] = E ---
__global__ void k_scanptr(const unsigned* __restrict__ tot, unsigned* __restrict__ ptr,
                          unsigned* __restrict__ nodeptr, int NL, int N) {
    __shared__ unsigned sums[B];
    int tid = threadIdx.x;
    int base = tid * 4;
    unsigned v[4]; unsigned loc = 0;
#pragma unroll
    for (int q = 0; q < 4; ++q) {
        int i = base + q;
        v[q] = (i < NL) ? tot[i] : 0u;
        loc += v[q];
    }
    sums[tid] = loc;
    __syncthreads();
    for (int off = 1; off < B; off <<= 1) {
        unsigned add = (tid >= off) ? sums[tid - off] : 0u;
        __syncthreads();
        sums[tid] += add;
        __syncthreads();
    }
    unsigned run = sums[tid] - loc;
#pragma unroll
    for (int q = 0; q < 4; ++q) {
        int i = base + q;
        if (i < NL) ptr[i] = run;
        run += v[q];
    }
    if (tid == B - 1) { ptr[NL] = run; nodeptr[N] = run; }
}

// --- placement v2: LDS counting sort by leaf, then run-coalesced 8B record writes ---
__global__ void __launch_bounds__(B)
k_place(const int* __restrict__ row, const int* __restrict__ col, const float* __restrict__ ew,
        const unsigned* __restrict__ bh, const unsigned* __restrict__ ptr,
        uint2* __restrict__ rec, int E, int NL) {
    __shared__ unsigned short l_idx[CH];
    __shared__ unsigned lscan[MAXNL];
    __shared__ unsigned lctr[MAXNL];
    __shared__ unsigned sums[B];
    int tid = threadIdx.x;
    int base = blockIdx.x * CH;
    int end = base + CH < E ? base + CH : E;
    int cnt = end - base;

    for (int i = tid; i < NL; i += B) lctr[i] = 0u;
    __syncthreads();
    for (int j = tid; j < cnt; j += B)
        atomicAdd(&lctr[col[base + j] >> LSH], 1u);
    __syncthreads();
    // block scan over NL bins (thread owns 4 bins)
    unsigned v[4]; unsigned loc = 0;
    int b0 = tid * 4;
#pragma unroll
    for (int q = 0; q < 4; ++q) { int i = b0 + q; v[q] = (i < NL) ? lctr[i] : 0u; loc += v[q]; }
    sums[tid] = loc;
    __syncthreads();
    for (int off = 1; off < B; off <<= 1) {
        unsigned add = (tid >= off) ? sums[tid - off] : 0u;
        __syncthreads();
        sums[tid] += add;
        __syncthreads();
    }
    unsigned run = sums[tid] - loc;
#pragma unroll
    for (int q = 0; q < 4; ++q) { int i = b0 + q; if (i < NL) lscan[i] = run; run += v[q]; }
    __syncthreads();
    for (int i = tid; i < NL; i += B) lctr[i] = lscan[i];
    __syncthreads();
    // place local indices in leaf-sorted order
    for (int j = tid; j < cnt; j += B) {
        int lf = col[base + j] >> LSH;
        unsigned pos = atomicAdd(&lctr[lf], 1u);
        l_idx[pos] = (unsigned short)j;
    }
    __syncthreads();
    // write out: sorted slot j -> global ptr[leaf] + chunk offset + rank; coalesced runs
    const unsigned* myb = bh + (size_t)blockIdx.x * NL;
    for (int j = tid; j < cnt; j += B) {
        int e = base + l_idx[j];
        int c = col[e];
        int lf = c >> LSH;
        unsigned outp = ptr[lf] + myb[lf] + ((unsigned)j - lscan[lf]);
        rec[outp] = make_uint2(((unsigned)row[e] << 6) | (unsigned)(c & (LNODES - 1)),
                               __float_as_uint(ew[e]));
    }
}

// --- second-level sort (by node within leaf) + degree -> dinv + nodeptr ---
__global__ void __launch_bounds__(B)
k_sort2(const uint2* __restrict__ rec, const unsigned* __restrict__ ptr,
        unsigned short* __restrict__ srow2, float* __restrict__ sew2,
        unsigned* __restrict__ nodeptr, float* __restrict__ dinv, int N) {
    __shared__ unsigned hist[LNODES];
    __shared__ float dacc[LNODES];
    __shared__ unsigned start[LNODES];
    int l = blockIdx.x, tid = threadIdx.x;
    if (tid < LNODES) { hist[tid] = 0u; dacc[tid] = 0.f; }
    __syncthreads();
    int seg = (int)ptr[l], end = (int)ptr[l + 1];
    for (int j = seg + tid; j < end; j += B) {
        uint2 u = rec[j];
        int c = (int)(u.x & (LNODES - 1));
        atomicAdd(&hist[c], 1u);
        atomicAdd(&dacc[c], __uint_as_float(u.y));
    }
    __syncthreads();
    if (tid < LNODES) {  // one wave -> shfl scan
        unsigned v = hist[tid];
        unsigned sum = v;
        for (int off = 1; off < LNODES; off <<= 1) {
            unsigned o = __shfl_up(sum, off, 64);
            if (tid >= off) sum += o;
        }
        unsigned st = (unsigned)seg + sum - v;  // exclusive
        start[tid] = st;
        int n = l * LNODES + tid;
        if (n < N) {
            nodeptr[n] = st;
            dinv[n] = rsqrtf(1.0f + dacc[tid]);
        }
    }
    __syncthreads();
    for (int j = seg + tid; j < end; j += B) {
        uint2 u = rec[j];
        int c = (int)(u.x & (LNODES - 1));
        unsigned pos = atomicAdd(&start[c], 1u);
        srow2[pos] = (unsigned short)(u.x >> 6);
        sew2[pos]  = __uint_as_float(u.y);
    }
}

// --- fold dinv[src] into edge weight ---
__global__ void k_prescale(const unsigned short* __restrict__ srow2, float* __restrict__ sew2,
                           const float* __restrict__ dinv, int E) {
    int j = blockIdx.x * B + threadIdx.x;
    if (j < E) sew2[j] *= dinv[srow2[j]];
}

// --- projection: h0 = x @ W^T ---
__global__ void k_proj(const float* __restrict__ x, const float* __restrict__ W,
                       float* __restrict__ y, int N) {
    __shared__ float sW[OUT_CH * (IN_CH + 1)];
    for (int i = threadIdx.x; i < OUT_CH * IN_CH; i += blockDim.x) {
        int o = i >> 7, k = i & 127;
        sW[o * (IN_CH + 1) + k] = W[i];
    }
    __syncthreads();
    int t = threadIdx.x;
    int n = blockIdx.x * 16 + (t >> 4);
    int o = t & 15;
    if (n >= N) return;
    const float* xr = x + (size_t)n * IN_CH;
    const float* wr = sW + o * (IN_CH + 1);
    float acc = 0.0f;
#pragma unroll
    for (int k = 0; k < IN_CH; k += 4) {
        float4 xv = *reinterpret_cast<const float4*>(xr + k);
        acc += xv.x * wr[k] + xv.y * wr[k + 1] + xv.z * wr[k + 2] + xv.w * wr[k + 3];
    }
    y[(size_t)n * OUT_CH + o] = acc;
}

// --- CSR hop: 16 threads per node, register accumulation, no atomics ---
template <bool FINAL>
__global__ void __launch_bounds__(B)
k_hop_csr(const unsigned short* __restrict__ srow2, const float* __restrict__ sew2,
          const unsigned* __restrict__ nodeptr, const float* __restrict__ dinv,
          const float* __restrict__ hin, float* __restrict__ hout, int N) {
    int t = blockIdx.x * B + threadIdx.x;
    int n = t >> 4, ch = t & 15;
    if (n >= N) return;
    int j0 = (int)nodeptr[n], j1 = (int)nodeptr[n + 1];
    float acc = 0.f;
    int j = j0;
    for (; j + 1 < j1; j += 2) {  // 2-wide for ILP
        int r0 = srow2[j], r1 = srow2[j + 1];
        float w0 = sew2[j], w1 = sew2[j + 1];
        acc += w0 * hin[(size_t)r0 * OUT_CH + ch] + w1 * hin[(size_t)r1 * OUT_CH + ch];
    }
    if (j < j1) {
        int r = srow2[j];
        acc += sew2[j] * hin[(size_t)r * OUT_CH + ch];
    }
    float d = dinv[n];
    float v = d * (d * hin[(size_t)n * OUT_CH + ch] + acc);
    if (!FINAL) {
        hout[(size_t)n * OUT_CH + ch] = v;
    } else {
        float m = v;
#pragma unroll
        for (int off = 1; off < 16; off <<= 1) m = fmaxf(m, __shfl_xor(m, off, 16));
        float s = expf(v - m);
#pragma unroll
        for (int off = 1; off < 16; off <<= 1) s += __shfl_xor(s, off, 16);
        hout[(size_t)n * OUT_CH + ch] = v - m - logf(s);
    }
}

// ================= fallback path (proven r2 structure) =================

__global__ void fb_deginit(float* deg, int N) {
    int i = blockIdx.x * blockDim.x + threadIdx.x;
    if (i < N) deg[i] = 1.0f;
}
__global__ void fb_deg(const int* __restrict__ col, const float* __restrict__ ew,
                       float* deg, int E) {
    int e = blockIdx.x * blockDim.x + threadIdx.x;
    if (e < E) atomicAdd(&deg[col[e]], ew[e]);
}
__global__ void fb_dinv(const float* __restrict__ deg, float* dinv, int N) {
    int i = blockIdx.x * blockDim.x + threadIdx.x;
    if (i < N) dinv[i] = rsqrtf(deg[i]);
}
__global__ void fb_selfinit(const float* __restrict__ hin, const float* __restrict__ dinv,
                            float* __restrict__ hout, int N) {
    int idx = blockIdx.x * blockDim.x + threadIdx.x;
    if (idx < N * OUT_CH) {
        float d = dinv[idx >> 4];
        hout[idx] = d * d * hin[idx];
    }
}
__global__ void fb_scat(const int* __restrict__ row, const int* __restrict__ col,
                        const float* __restrict__ ew, const float* __restrict__ dinv,
                        const float* __restrict__ hin, float* __restrict__ hout, int E) {
    long long idx = (long long)blockIdx.x * blockDim.x + threadIdx.x;
    int e = (int)(idx >> 4);
    int c = (int)(idx & 15);
    if (e >= E) return;
    int r = row[e], cl = col[e];
    float nv = dinv[r] * ew[e] * dinv[cl];
    atomicAdd(&hout[(size_t)cl * OUT_CH + c], nv * hin[(size_t)r * OUT_CH + c]);
}
__global__ void fb_lsm(const float* __restrict__ h, float* __restrict__ out, int N) {
    int n = blockIdx.x * blockDim.x + threadIdx.x;
    if (n >= N) return;
    const float* hr = h + (size_t)n * OUT_CH;
    float v[OUT_CH];
#pragma unroll
    for (int i = 0; i < OUT_CH; i++) v[i] = hr[i];
    float m = v[0];
#pragma unroll
    for (int i = 1; i < OUT_CH; i++) m = fmaxf(m, v[i]);
    float s = 0.0f;
#pragma unroll
    for (int i = 0; i < OUT_CH; i++) s += expf(v[i] - m);
    float lse = m + logf(s);
    float* orow = out + (size_t)n * OUT_CH;
#pragma unroll
    for (int i = 0; i < OUT_CH; i++) orow[i] = v[i] - lse;
}

// ================= launch =================

extern "C" void kernel_launch(void* const* d_in, const int* in_sizes, int n_in,
                              void* d_out, int out_size, void* d_ws, size_t ws_size,
                              hipStream_t stream) {
    const float* x  = (const float*)d_in[0];
    const float* W  = (const float*)d_in[1];
    const float* ew = (const float*)d_in[2];
    const int*   ei = (const int*)d_in[3];  // harness pushes int64 as int32

    int N = in_sizes[0] / IN_CH;
    int E = in_sizes[2];
    const int* row = ei;       // source
    const int* col = ei + E;   // target

    auto al = [](size_t v) { return (v + 255) & ~(size_t)255; };
    size_t N16 = (size_t)N * OUT_CH;

    int NL = (N + LNODES - 1) >> LSH;
    int G  = (E + CH - 1) / CH;

    // layout: srow2(∪bh) | sew2 | rec(∪h0,h1) | tot | ptr | nodeptr | dinv
    size_t o_srow2 = 0;
    size_t o_sew2  = o_srow2 + al((size_t)E * 2);
    size_t o_rec   = o_sew2  + al((size_t)E * 4);
    size_t o_tot   = o_rec   + al((size_t)E * 8);
    size_t o_ptr   = o_tot   + al((size_t)NL * 4);
    size_t o_nptr  = o_ptr   + al((size_t)(NL + 1) * 4);
    size_t o_dinv  = o_nptr  + al((size_t)(N + 1) * 4);
    size_t need    = o_dinv  + al((size_t)N * 4);

    bool bh_fits = ((size_t)G * NL * 4 <= al((size_t)E * 2));        // bh aliases srow2
    bool h_fits  = (2 * al(N16 * 4) <= al((size_t)E * 8));           // h0+h1 alias rec

    char* ws = (char*)d_ws;

    if (NL <= MAXNL && G <= MAXG && N <= 65536 && bh_fits && h_fits && need <= ws_size) {
        unsigned short* srow2 = (unsigned short*)(ws + o_srow2);
        unsigned*       bh    = (unsigned*)(ws + o_srow2);       // dead before srow2 written
        float*          sew2  = (float*)(ws + o_sew2);
        uint2*          rec   = (uint2*)(ws + o_rec);
        float*          h0    = (float*)(ws + o_rec);            // written after rec dead
        float*          h1    = (float*)(ws + o_rec + al(N16 * 4));
        unsigned*       tot   = (unsigned*)(ws + o_tot);
        unsigned*       ptr   = (unsigned*)(ws + o_ptr);
        unsigned*       nptr  = (unsigned*)(ws + o_nptr);
        float*          dinv  = (float*)(ws + o_dinv);

        k_hist    <<<G,  B, 0, stream>>>(col, bh, E, NL);
        k_colscan <<<NL, B, 0, stream>>>(bh, tot, G, NL);
        k_scanptr <<<1,  B, 0, stream>>>(tot, ptr, nptr, NL, N);
        k_place   <<<G,  B, 0, stream>>>(row, col, ew, bh, ptr, rec, E, NL);
        k_sort2   <<<NL, B, 0, stream>>>(rec, ptr, srow2, sew2, nptr, dinv, N);
        k_prescale<<<(E + B - 1) / B, B, 0, stream>>>(srow2, sew2, dinv, E);
        k_proj    <<<(N + 15) / 16, B, 0, stream>>>(x, W, h0, N);   // clobbers rec (dead)
        int gH = (int)(((size_t)N * OUT_CH + B - 1) / B);
        k_hop_csr<false><<<gH, B, 0, stream>>>(srow2, sew2, nptr, dinv, h0, h1, N);
        k_hop_csr<true ><<<gH, B, 0, stream>>>(srow2, sew2, nptr, dinv, h1, (float*)d_out, N);
    } else {
        // ---- fallback (r2-style, ~6.8 MB ws) ----
        size_t f_deg  = 0;
        size_t f_dinv = f_deg  + al((size_t)N * 4);
        size_t f_h0   = f_dinv + al((size_t)N * 4);
        size_t f_h1   = f_h0   + al(N16 * 4);
        float* deg  = (float*)(ws + f_deg);
        float* dinv = (float*)(ws + f_dinv);
        float* h0   = (float*)(ws + f_h0);
        float* h1   = (float*)(ws + f_h1);

        int gN   = (N + B - 1) / B;
        int gE   = (E + B - 1) / B;
        int gN16 = (N * OUT_CH + B - 1) / B;
        long long scat = (long long)E * OUT_CH;
        int gScat = (int)((scat + B - 1) / B);

        fb_deginit<<<gN, B, 0, stream>>>(deg, N);
        fb_deg<<<gE, B, 0, stream>>>(col, ew, deg, E);
        fb_dinv<<<gN, B, 0, stream>>>(deg, dinv, N);
        k_proj<<<(N + 15) / 16, B, 0, stream>>>(x, W, h0, N);
        float* hin = h0; float* hout = h1;
        for (int k = 0; k < 2; k++) {
            fb_selfinit<<<gN16, B, 0, stream>>>(hin, dinv, hout, N);
            fb_scat<<<gScat, B, 0, stream>>>(row, col, ew, dinv, hin, hout, E);
            float* t = hin; hin = hout; hout = t;
        }
        fb_lsm<<<gN, B, 0, stream>>>(hin, (float*)d_out, N);
    }
}

// Round 9
// 145.430 us; speedup vs baseline: 3.2194x; 1.0678x over previous
//
#include <hip/hip_runtime.h>
#include <math.h>

#define IN_CH 128
#define OUT_CH 16
#define B 256
#define CH 4096           // edges per sort chunk
#define LSH 6             // leaf = node >> 6  (64 nodes per leaf)
#define LNODES 64
#define MAXNL 1024
#define MAXG 512

// ================= main path: two-level counting sort -> per-node CSR, g-space hops =================

// --- per-chunk leaf histogram ---
__global__ void k_hist(const int* __restrict__ col, unsigned* __restrict__ bh, int E, int NL) {
    __shared__ unsigned hc[MAXNL];
    for (int i = threadIdx.x; i < NL; i += B) hc[i] = 0u;
    __syncthreads();
    int base = blockIdx.x * CH;
    int end = base + CH < E ? base + CH : E;
    for (int e = base + threadIdx.x; e < end; e += B)
        atomicAdd(&hc[col[e] >> LSH], 1u);
    __syncthreads();
    unsigned* out = bh + (size_t)blockIdx.x * NL;
    for (int i = threadIdx.x; i < NL; i += B) out[i] = hc[i];
}

// --- per-leaf exclusive scan over chunks (loops over G with carry); totals out ---
__global__ void k_colscan(unsigned* __restrict__ bh, unsigned* __restrict__ tot, int G, int NL) {
    int j = blockIdx.x;
    __shared__ unsigned s[B];
    int tid = threadIdx.x;
    unsigned carry = 0;
    for (int g0 = 0; g0 < G; g0 += B) {
        __syncthreads();
        int g = g0 + tid;
        unsigned v = (g < G) ? bh[(size_t)g * NL + j] : 0u;
        s[tid] = v;
        __syncthreads();
        for (int off = 1; off < B; off <<= 1) {
            unsigned add = (tid >= off) ? s[tid - off] : 0u;
            __syncthreads();
            s[tid] += add;
            __syncthreads();
        }
        if (g < G) bh[(size_t)g * NL + j] = carry + s[tid] - v;
        carry += s[B - 1];
    }
    if (tid == 0) tot[j] = carry;
}

// --- placement: local leaf-base scan + LDS counting sort + run-coalesced 8B record writes ---
__global__ void __launch_bounds__(B)
k_place(const int* __restrict__ row, const int* __restrict__ col, const float* __restrict__ ew,
        const unsigned* __restrict__ bh, const unsigned* __restrict__ tot,
        uint2* __restrict__ rec, int E, int NL) {
    __shared__ unsigned short l_idx[CH];
    __shared__ unsigned gbase[MAXNL];
    __shared__ unsigned lscan[MAXNL];
    __shared__ unsigned lctr[MAXNL];
    __shared__ unsigned sums[B];
    int tid = threadIdx.x;
    int base = blockIdx.x * CH;
    int end = base + CH < E ? base + CH : E;
    int cnt = end - base;

    // scan tot -> gbase (global leaf bases)
    {
        int b0 = tid * 4; unsigned v[4]; unsigned loc = 0;
#pragma unroll
        for (int q = 0; q < 4; ++q) { int i = b0 + q; v[q] = (i < NL) ? tot[i] : 0u; loc += v[q]; }
        sums[tid] = loc; __syncthreads();
        for (int off = 1; off < B; off <<= 1) {
            unsigned a = (tid >= off) ? sums[tid - off] : 0u;
            __syncthreads(); sums[tid] += a; __syncthreads();
        }
        unsigned run = sums[tid] - loc;
#pragma unroll
        for (int q = 0; q < 4; ++q) { int i = b0 + q; if (i < NL) gbase[i] = run; run += v[q]; }
    }
    for (int i = tid; i < NL; i += B) lctr[i] = 0u;
    __syncthreads();
    for (int j = tid; j < cnt; j += B)
        atomicAdd(&lctr[col[base + j] >> LSH], 1u);
    __syncthreads();
    // scan lctr -> lscan (local chunk bases)
    {
        int b0 = tid * 4; unsigned v[4]; unsigned loc = 0;
#pragma unroll
        for (int q = 0; q < 4; ++q) { int i = b0 + q; v[q] = (i < NL) ? lctr[i] : 0u; loc += v[q]; }
        sums[tid] = loc; __syncthreads();
        for (int off = 1; off < B; off <<= 1) {
            unsigned a = (tid >= off) ? sums[tid - off] : 0u;
            __syncthreads(); sums[tid] += a; __syncthreads();
        }
        unsigned run = sums[tid] - loc;
#pragma unroll
        for (int q = 0; q < 4; ++q) { int i = b0 + q; if (i < NL) lscan[i] = run; run += v[q]; }
    }
    __syncthreads();
    for (int i = tid; i < NL; i += B) lctr[i] = lscan[i];
    __syncthreads();
    // place local indices in leaf-sorted order
    for (int j = tid; j < cnt; j += B) {
        int lf = col[base + j] >> LSH;
        unsigned pos = atomicAdd(&lctr[lf], 1u);
        l_idx[pos] = (unsigned short)j;
    }
    __syncthreads();
    // write out: sorted slot j -> gbase[leaf] + chunk offset + rank (coalesced runs)
    const unsigned* myb = bh + (size_t)blockIdx.x * NL;
    for (int j = tid; j < cnt; j += B) {
        int e = base + l_idx[j];
        int c = col[e];
        int lf = c >> LSH;
        unsigned outp = gbase[lf] + myb[lf] + ((unsigned)j - lscan[lf]);
        rec[outp] = make_uint2(((unsigned)row[e] << 6) | (unsigned)(c & (LNODES - 1)),
                               __float_as_uint(ew[e]));
    }
}

// --- second-level sort (by node within leaf): rec2 = {row, w}, nodeptr, dinv ---
__global__ void __launch_bounds__(B)
k_sort2(const uint2* __restrict__ rec, const unsigned* __restrict__ tot,
        uint2* __restrict__ rec2, unsigned* __restrict__ nodeptr,
        float* __restrict__ dinv, int N, int NL) {
    __shared__ unsigned sums[B];
    __shared__ unsigned hist[LNODES];
    __shared__ float dacc[LNODES];
    __shared__ unsigned start[LNODES];
    __shared__ unsigned s_seg[2];
    int l = blockIdx.x, tid = threadIdx.x;
    // local scan of tot to find this leaf's [seg, segend)
    {
        int b0 = tid * 4; unsigned v[4]; unsigned loc = 0;
#pragma unroll
        for (int q = 0; q < 4; ++q) { int i = b0 + q; v[q] = (i < NL) ? tot[i] : 0u; loc += v[q]; }
        sums[tid] = loc; __syncthreads();
        for (int off = 1; off < B; off <<= 1) {
            unsigned a = (tid >= off) ? sums[tid - off] : 0u;
            __syncthreads(); sums[tid] += a; __syncthreads();
        }
        unsigned run = sums[tid] - loc;
#pragma unroll
        for (int q = 0; q < 4; ++q) {
            int i = b0 + q;
            if (i == l) { s_seg[0] = run; s_seg[1] = run + v[q]; }
            run += v[q];
        }
    }
    if (tid < LNODES) { hist[tid] = 0u; dacc[tid] = 0.f; }
    __syncthreads();
    int seg = (int)s_seg[0], end = (int)s_seg[1];
    for (int j = seg + tid; j < end; j += B) {
        uint2 u = rec[j];
        int c = (int)(u.x & (LNODES - 1));
        atomicAdd(&hist[c], 1u);
        atomicAdd(&dacc[c], __uint_as_float(u.y));
    }
    __syncthreads();
    if (tid < LNODES) {  // one wave -> shfl scan
        unsigned v = hist[tid];
        unsigned sum = v;
        for (int off = 1; off < LNODES; off <<= 1) {
            unsigned o = __shfl_up(sum, off, 64);
            if (tid >= off) sum += o;
        }
        unsigned st = (unsigned)seg + sum - v;  // exclusive
        start[tid] = st;
        int n = l * LNODES + tid;
        if (n < N) {
            nodeptr[n] = st;
            dinv[n] = rsqrtf(1.0f + dacc[tid]);
        }
    }
    if (l == NL - 1 && tid == 0) nodeptr[N] = (unsigned)end;
    __syncthreads();
    for (int j = seg + tid; j < end; j += B) {
        uint2 u = rec[j];
        int c = (int)(u.x & (LNODES - 1));
        unsigned pos = atomicAdd(&start[c], 1u);
        rec2[pos] = make_uint2(u.x >> 6, u.y);
    }
}

// --- projection into g-space: g0 = dinv ⊙ (x @ W^T) ---
__global__ void k_proj(const float* __restrict__ x, const float* __restrict__ W,
                       const float* __restrict__ dinv, float* __restrict__ y, int N) {
    __shared__ float sW[OUT_CH * (IN_CH + 1)];
    for (int i = threadIdx.x; i < OUT_CH * IN_CH; i += blockDim.x) {
        int o = i >> 7, k = i & 127;
        sW[o * (IN_CH + 1) + k] = W[i];
    }
    __syncthreads();
    int t = threadIdx.x;
    int n = blockIdx.x * 16 + (t >> 4);
    int o = t & 15;
    if (n >= N) return;
    const float* xr = x + (size_t)n * IN_CH;
    const float* wr = sW + o * (IN_CH + 1);
    float acc = 0.0f;
#pragma unroll
    for (int k = 0; k < IN_CH; k += 4) {
        float4 xv = *reinterpret_cast<const float4*>(xr + k);
        acc += xv.x * wr[k] + xv.y * wr[k + 1] + xv.z * wr[k + 2] + xv.w * wr[k + 3];
    }
    y[(size_t)n * OUT_CH + o] = dinv[n] * acc;
}

// --- CSR hop in g-space: 16 threads/node, register accumulation, no atomics ---
// !FINAL: gout[n] = dinv[n]^2 * (gin[n] + sum w*gin[r])
//  FINAL: out[n]  = log_softmax(dinv[n] * (gin[n] + sum w*gin[r]))
template <bool FINAL>
__global__ void __launch_bounds__(B)
k_hop(const uint2* __restrict__ rec2, const unsigned* __restrict__ nodeptr,
      const float* __restrict__ dinv, const float* __restrict__ gin,
      float* __restrict__ out, int N) {
    int t = blockIdx.x * B + threadIdx.x;
    int n = t >> 4, ch = t & 15;
    if (n >= N) return;
    int j0 = (int)nodeptr[n], j1 = (int)nodeptr[n + 1];
    float acc = 0.f;
    int j = j0;
    for (; j + 1 < j1; j += 2) {  // 2-wide for ILP
        uint2 u0 = rec2[j], u1 = rec2[j + 1];
        acc += __uint_as_float(u0.y) * gin[(size_t)u0.x * OUT_CH + ch]
             + __uint_as_float(u1.y) * gin[(size_t)u1.x * OUT_CH + ch];
    }
    if (j < j1) {
        uint2 u = rec2[j];
        acc += __uint_as_float(u.y) * gin[(size_t)u.x * OUT_CH + ch];
    }
    float d = dinv[n];
    float s = gin[(size_t)n * OUT_CH + ch] + acc;
    if (!FINAL) {
        out[(size_t)n * OUT_CH + ch] = d * d * s;
    } else {
        float v = d * s;
        float m = v;
#pragma unroll
        for (int off = 1; off < 16; off <<= 1) m = fmaxf(m, __shfl_xor(m, off, 16));
        float sm = expf(v - m);
#pragma unroll
        for (int off = 1; off < 16; off <<= 1) sm += __shfl_xor(sm, off, 16);
        out[(size_t)n * OUT_CH + ch] = v - m - logf(sm);
    }
}

// ================= fallback path (proven r2 structure) =================

__global__ void fb_deginit(float* deg, int N) {
    int i = blockIdx.x * blockDim.x + threadIdx.x;
    if (i < N) deg[i] = 1.0f;
}
__global__ void fb_deg(const int* __restrict__ col, const float* __restrict__ ew,
                       float* deg, int E) {
    int e = blockIdx.x * blockDim.x + threadIdx.x;
    if (e < E) atomicAdd(&deg[col[e]], ew[e]);
}
__global__ void fb_dinv(const float* __restrict__ deg, float* dinv, int N) {
    int i = blockIdx.x * blockDim.x + threadIdx.x;
    if (i < N) dinv[i] = rsqrtf(deg[i]);
}
__global__ void fb_proj(const float* __restrict__ x, const float* __restrict__ W,
                        float* __restrict__ y, int N) {
    __shared__ float sW[OUT_CH * (IN_CH + 1)];
    for (int i = threadIdx.x; i < OUT_CH * IN_CH; i += blockDim.x) {
        int o = i >> 7, k = i & 127;
        sW[o * (IN_CH + 1) + k] = W[i];
    }
    __syncthreads();
    int t = threadIdx.x;
    int n = blockIdx.x * 16 + (t >> 4);
    int o = t & 15;
    if (n >= N) return;
    const float* xr = x + (size_t)n * IN_CH;
    const float* wr = sW + o * (IN_CH + 1);
    float acc = 0.0f;
#pragma unroll
    for (int k = 0; k < IN_CH; k += 4) {
        float4 xv = *reinterpret_cast<const float4*>(xr + k);
        acc += xv.x * wr[k] + xv.y * wr[k + 1] + xv.z * wr[k + 2] + xv.w * wr[k + 3];
    }
    y[(size_t)n * OUT_CH + o] = acc;
}
__global__ void fb_selfinit(const float* __restrict__ hin, const float* __restrict__ dinv,
                            float* __restrict__ hout, int N) {
    int idx = blockIdx.x * blockDim.x + threadIdx.x;
    if (idx < N * OUT_CH) {
        float d = dinv[idx >> 4];
        hout[idx] = d * d * hin[idx];
    }
}
__global__ void fb_scat(const int* __restrict__ row, const int* __restrict__ col,
                        const float* __restrict__ ew, const float* __restrict__ dinv,
                        const float* __restrict__ hin, float* __restrict__ hout, int E) {
    long long idx = (long long)blockIdx.x * blockDim.x + threadIdx.x;
    int e = (int)(idx >> 4);
    int c = (int)(idx & 15);
    if (e >= E) return;
    int r = row[e], cl = col[e];
    float nv = dinv[r] * ew[e] * dinv[cl];
    atomicAdd(&hout[(size_t)cl * OUT_CH + c], nv * hin[(size_t)r * OUT_CH + c]);
}
__global__ void fb_lsm(const float* __restrict__ h, float* __restrict__ out, int N) {
    int n = blockIdx.x * blockDim.x + threadIdx.x;
    if (n >= N) return;
    const float* hr = h + (size_t)n * OUT_CH;
    float v[OUT_CH];
#pragma unroll
    for (int i = 0; i < OUT_CH; i++) v[i] = hr[i];
    float m = v[0];
#pragma unroll
    for (int i = 1; i < OUT_CH; i++) m = fmaxf(m, v[i]);
    float s = 0.0f;
#pragma unroll
    for (int i = 0; i < OUT_CH; i++) s += expf(v[i] - m);
    float lse = m + logf(s);
    float* orow = out + (size_t)n * OUT_CH;
#pragma unroll
    for (int i = 0; i < OUT_CH; i++) orow[i] = v[i] - lse;
}

// ================= launch =================

extern "C" void kernel_launch(void* const* d_in, const int* in_sizes, int n_in,
                              void* d_out, int out_size, void* d_ws, size_t ws_size,
                              hipStream_t stream) {
    const float* x  = (const float*)d_in[0];
    const float* W  = (const float*)d_in[1];
    const float* ew = (const float*)d_in[2];
    const int*   ei = (const int*)d_in[3];  // harness pushes int64 as int32

    int N = in_sizes[0] / IN_CH;
    int E = in_sizes[2];
    const int* row = ei;       // source
    const int* col = ei + E;   // target

    auto al = [](size_t v) { return (v + 255) & ~(size_t)255; };
    size_t N16 = (size_t)N * OUT_CH;

    int NL = (N + LNODES - 1) >> LSH;
    int G  = (E + CH - 1) / CH;

    // layout: rec2(∪bh) | rec(∪g0,g1) | tot | nodeptr | dinv
    size_t o_rec2 = 0;
    size_t o_rec  = o_rec2 + al((size_t)E * 8);
    size_t o_tot  = o_rec  + al((size_t)E * 8);
    size_t o_nptr = o_tot  + al((size_t)NL * 4);
    size_t o_dinv = o_nptr + al((size_t)(N + 1) * 4);
    size_t need   = o_dinv + al((size_t)N * 4);

    bool bh_fits = ((size_t)G * NL * 4 <= al((size_t)E * 8));   // bh aliases rec2
    bool g_fits  = (2 * al(N16 * 4) <= al((size_t)E * 8));      // g0+g1 alias rec

    char* ws = (char*)d_ws;

    if (NL <= MAXNL && G <= MAXG && N <= MAXNL * LNODES && bh_fits && g_fits && need <= ws_size) {
        uint2*    rec2 = (uint2*)(ws + o_rec2);
        unsigned* bh   = (unsigned*)(ws + o_rec2);   // dead before rec2 written (k_sort2)
        uint2*    rec  = (uint2*)(ws + o_rec);
        float*    g0   = (float*)(ws + o_rec);       // written after rec dead (k_proj)
        float*    g1   = (float*)(ws + o_rec + al(N16 * 4));
        unsigned* tot  = (unsigned*)(ws + o_tot);
        unsigned* nptr = (unsigned*)(ws + o_nptr);
        float*    dinv = (float*)(ws + o_dinv);

        k_hist   <<<G,  B, 0, stream>>>(col, bh, E, NL);
        k_colscan<<<NL, B, 0, stream>>>(bh, tot, G, NL);
        k_place  <<<G,  B, 0, stream>>>(row, col, ew, bh, tot, rec, E, NL);
        k_sort2  <<<NL, B, 0, stream>>>(rec, tot, rec2, nptr, dinv, N, NL);
        k_proj   <<<(N + 15) / 16, B, 0, stream>>>(x, W, dinv, g0, N);  // clobbers rec (dead)
        int gH = (int)(((size_t)N * OUT_CH + B - 1) / B);
        k_hop<false><<<gH, B, 0, stream>>>(rec2, nptr, dinv, g0, g1, N);
        k_hop<true ><<<gH, B, 0, stream>>>(rec2, nptr, dinv, g1, (float*)d_out, N);
    } else {
        // ---- fallback (r2-style, ~6.8 MB ws) ----
        size_t f_deg  = 0;
        size_t f_dinv = f_deg  + al((size_t)N * 4);
        size_t f_h0   = f_dinv + al((size_t)N * 4);
        size_t f_h1   = f_h0   + al(N16 * 4);
        float* deg  = (float*)(ws + f_deg);
        float* dinv = (float*)(ws + f_dinv);
        float* h0   = (float*)(ws + f_h0);
        float* h1   = (float*)(ws + f_h1);

        int gN   = (N + B - 1) / B;
        int gE   = (E + B - 1) / B;
        int gN16 = (N * OUT_CH + B - 1) / B;
        long long scat = (long long)E * OUT_CH;
        int gScat = (int)((scat + B - 1) / B);

        fb_deginit<<<gN, B, 0, stream>>>(deg, N);
        fb_deg<<<gE, B, 0, stream>>>(col, ew, deg, E);
        fb_dinv<<<gN, B, 0, stream>>>(deg, dinv, N);
        fb_proj<<<(N + 15) / 16, B, 0, stream>>>(x, W, h0, N);
        float* hin = h0; float* hout = h1;
        for (int k = 0; k < 2; k++) {
            fb_selfinit<<<gN16, B, 0, stream>>>(hin, dinv, hout, N);
            fb_scat<<<gScat, B, 0, stream>>>(row, col, ew, dinv, hin, hout, E);
            float* t = hin; hin = hout; hout = t;
        }
        fb_lsm<<<gN, B, 0, stream>>>(hin, (float*)d_out, N);
    }
}